// Round 1
// baseline (2002.448 us; speedup 1.0000x reference)
//
#include <hip/hip_runtime.h>
#include <math.h>

#define Bsz  4
#define Tlen 4096
#define Cdim 512
#define CUT  (-35.0f)   // exp(-35) ~ 6e-16: neglected decay tail is ~1e-12 absolute

// ---------------------------------------------------------------------------
// Kernel A: prefix sums of ln(gamma).  L[t] = sum_{j<t} ln g_j  (t=0..T),
// A[t] = ln g_t + L[t].  gamma_t = linspace(0.96, 0.99, T).
// ---------------------------------------------------------------------------
__global__ void scan_kernel(float* __restrict__ L, float* __restrict__ A) {
    __shared__ float sums[256];
    int tid = threadIdx.x;
    float lg[16];
    float local = 0.f;
    int base = tid * 16;
#pragma unroll
    for (int i = 0; i < 16; ++i) {
        int t = base + i;
        float g = 0.96f + 0.03f * ((float)t * (1.0f / 4095.0f));
        lg[i] = logf(g);
        local += lg[i];
    }
    sums[tid] = local;
    __syncthreads();
    for (int off = 1; off < 256; off <<= 1) {
        float v = sums[tid];
        if (tid >= off) v += sums[tid - off];
        __syncthreads();
        sums[tid] = v;
        __syncthreads();
    }
    float pre = (tid == 0) ? 0.f : sums[tid - 1];
#pragma unroll
    for (int i = 0; i < 16; ++i) {
        int t = base + i;
        L[t] = pre;
        A[t] = lg[i] + pre;      // same rounding as pre+lg below -> w(t,t)==1
        pre += lg[i];
    }
    if (tid == 255) L[Tlen] = pre;
}

// ---------------------------------------------------------------------------
// Kernel B: fused QKV projection.  [B*T,C] @ [C,C] + bias, three weight mats.
// 64x64 tiles, 256 threads, 4x4 micro-tile, fp32.
// ---------------------------------------------------------------------------
__global__ __launch_bounds__(256) void qkv_gemm(
    const float* __restrict__ X,
    const float* __restrict__ WQ, const float* __restrict__ bQ,
    const float* __restrict__ WK, const float* __restrict__ bK,
    const float* __restrict__ WV, const float* __restrict__ bV,
    float* __restrict__ Q, float* __restrict__ K, float* __restrict__ V) {
    __shared__ float As[16][68];   // [k][m], transposed store, padded
    __shared__ float Bs[16][68];   // [k][n]
    int tid = threadIdx.x;
    int mt = blockIdx.x;           // 0..255  (B*T/64)
    int nt = blockIdx.y;           // 0..23   (3*C/64)
    int mat = nt >> 3;
    int n0  = (nt & 7) * 64;
    const float* W    = (mat == 0) ? WQ : (mat == 1) ? WK : WV;
    const float* bias = (mat == 0) ? bQ : (mat == 1) ? bK : bV;
    float* Out        = (mat == 0) ? Q  : (mat == 1) ? K  : V;
    int m0 = mt * 64;
    int tx = tid & 15, ty = tid >> 4;
    int arow = tid >> 2, aq = tid & 3;     // A: 64 rows x 4 float4
    int brow = tid >> 4, bq = tid & 15;    // B: 16 rows x 16 float4

    float acc[4][4];
#pragma unroll
    for (int i = 0; i < 4; ++i)
#pragma unroll
        for (int j = 0; j < 4; ++j) acc[i][j] = 0.f;

    for (int kc = 0; kc < Cdim; kc += 16) {
        float4 av = *(const float4*)&X[(size_t)(m0 + arow) * Cdim + kc + aq * 4];
        float4 bv = *(const float4*)&W[(size_t)(kc + brow) * Cdim + n0 + bq * 4];
        __syncthreads();
        As[aq * 4 + 0][arow] = av.x;
        As[aq * 4 + 1][arow] = av.y;
        As[aq * 4 + 2][arow] = av.z;
        As[aq * 4 + 3][arow] = av.w;
        *(float4*)&Bs[brow][bq * 4] = bv;
        __syncthreads();
#pragma unroll
        for (int kk = 0; kk < 16; ++kk) {
            float4 a4 = *(const float4*)&As[kk][ty * 4];
            float4 b4 = *(const float4*)&Bs[kk][tx * 4];
            float aa[4] = {a4.x, a4.y, a4.z, a4.w};
            float bb[4] = {b4.x, b4.y, b4.z, b4.w};
#pragma unroll
            for (int i = 0; i < 4; ++i)
#pragma unroll
                for (int j = 0; j < 4; ++j) acc[i][j] += aa[i] * bb[j];
        }
    }
    float4 bb4 = *(const float4*)&bias[n0 + tx * 4];
    float bb[4] = {bb4.x, bb4.y, bb4.z, bb4.w};
#pragma unroll
    for (int i = 0; i < 4; ++i) {
        float4 o;
        o.x = acc[i][0] + bb[0];
        o.y = acc[i][1] + bb[1];
        o.z = acc[i][2] + bb[2];
        o.w = acc[i][3] + bb[3];
        *(float4*)&Out[(size_t)(m0 + ty * 4 + i) * Cdim + n0 + tx * 4] = o;
    }
}

// ---------------------------------------------------------------------------
// Kernel C: decay-weighted causal attention with tanh.
// O[b,t,:] = tanh( sum_{s<=t} exp(A[t]-L[s+1]) * (q_t.k_s) * V[b,s,:] )
// t-tile = 32 rows, s-tile = 64.  256 threads.  Window-pruned.
// 1 block/CU (LDS > 80KB on purpose) + longest-first dispatch for balance.
// ---------------------------------------------------------------------------
__global__ __launch_bounds__(256) void attn_kernel(
    const float* __restrict__ Qm, const float* __restrict__ Km,
    const float* __restrict__ Vm, const float* __restrict__ L,
    const float* __restrict__ A, float* __restrict__ O) {
    __shared__ float Qs[32][36];    // [k][t]
    __shared__ float Ks[32][68];    // [k][s]
    __shared__ float Ps[64][36];    // [s][t]
    __shared__ float Vs[64][236];   // [s][d-chunk 128] (padded to force 1 blk/CU)

    int tid = threadIdx.x;
    int bid = blockIdx.x;
    int ttile = 127 - (bid >> 2);   // longest-running tiles dispatched first
    int b = bid & 3;
    int t0 = ttile * 32;
    size_t bT = (size_t)b * Tlen;

    int tx = tid & 15;   // s-col group (phase1) / d group (phase2)
    int ty = tid >> 4;   // t-row group (2 rows)

    float acc[2][32];
#pragma unroll
    for (int i = 0; i < 2; ++i)
#pragma unroll
        for (int j = 0; j < 32; ++j) acc[i][j] = 0.f;

    float at0 = A[t0 + ty * 2];
    float at1 = A[t0 + ty * 2 + 1];
    float At0 = A[t0];

    int st_hi = ttile >> 1;          // last s-tile containing valid s<=t
    int s_lo = st_hi;
    for (int st = 0; st < st_hi; ++st) {
        if (At0 - L[st * 64 + 64] > CUT) { s_lo = st; break; }
    }

    for (int st = s_lo; st <= st_hi; ++st) {
        int s0 = st * 64;
        float p[2][4];
#pragma unroll
        for (int i = 0; i < 2; ++i)
#pragma unroll
            for (int j = 0; j < 4; ++j) p[i][j] = 0.f;

        // ---- phase 1: P = Q_tile . K_tile^T  (inner dim C, chunks of 32)
        for (int kc = 0; kc < Cdim; kc += 32) {
            int arow = tid >> 3, aq = tid & 7;   // 32 rows x 8 f4
            float4 qv = *(const float4*)&Qm[(bT + t0 + arow) * Cdim + kc + aq * 4];
            int i1 = tid + 256;
            int kr0 = tid >> 3, kq0 = tid & 7;   // 64 rows x 8 f4 (two passes)
            int kr1 = i1 >> 3,  kq1 = i1 & 7;
            float4 kv0 = *(const float4*)&Km[(bT + s0 + kr0) * Cdim + kc + kq0 * 4];
            float4 kv1 = *(const float4*)&Km[(bT + s0 + kr1) * Cdim + kc + kq1 * 4];
            __syncthreads();
            Qs[aq * 4 + 0][arow] = qv.x;
            Qs[aq * 4 + 1][arow] = qv.y;
            Qs[aq * 4 + 2][arow] = qv.z;
            Qs[aq * 4 + 3][arow] = qv.w;
            Ks[kq0 * 4 + 0][kr0] = kv0.x;
            Ks[kq0 * 4 + 1][kr0] = kv0.y;
            Ks[kq0 * 4 + 2][kr0] = kv0.z;
            Ks[kq0 * 4 + 3][kr0] = kv0.w;
            Ks[kq1 * 4 + 0][kr1] = kv1.x;
            Ks[kq1 * 4 + 1][kr1] = kv1.y;
            Ks[kq1 * 4 + 2][kr1] = kv1.z;
            Ks[kq1 * 4 + 3][kr1] = kv1.w;
            __syncthreads();
#pragma unroll
            for (int kk = 0; kk < 32; ++kk) {
                float2 a2 = *(const float2*)&Qs[kk][ty * 2];
                float4 b4 = *(const float4*)&Ks[kk][tx * 4];
                p[0][0] += a2.x * b4.x; p[0][1] += a2.x * b4.y;
                p[0][2] += a2.x * b4.z; p[0][3] += a2.x * b4.w;
                p[1][0] += a2.y * b4.x; p[1][1] += a2.y * b4.y;
                p[1][2] += a2.y * b4.z; p[1][3] += a2.y * b4.w;
            }
        }

        // ---- decay weights (diagonal weight is exactly 1; s>t masked to 0)
        {
            int t_0 = t0 + ty * 2, t_1 = t_0 + 1;
#pragma unroll
            for (int j = 0; j < 4; ++j) {
                int s = s0 + tx * 4 + j;
                float lsp = L[s + 1];
                float w0 = (s <= t_0) ? expf(at0 - lsp) : 0.f;
                float w1 = (s <= t_1) ? expf(at1 - lsp) : 0.f;
                p[0][j] *= w0;
                p[1][j] *= w1;
            }
        }
#pragma unroll
        for (int i = 0; i < 2; ++i)
#pragma unroll
            for (int j = 0; j < 4; ++j) Ps[tx * 4 + j][ty * 2 + i] = p[i][j];

        // ---- phase 2: O_acc += P . V_tile  (d in 4 chunks of 128)
#pragma unroll
        for (int dc = 0; dc < 4; ++dc) {
            __syncthreads();   // prev reads of Vs done; also makes Ps visible (dc=0)
#pragma unroll
            for (int pass = 0; pass < 8; ++pass) {
                int idx = pass * 256 + tid;
                int srow = idx >> 5, f4c = idx & 31;
                *(float4*)&Vs[srow][f4c * 4] =
                    *(const float4*)&Vm[(bT + s0 + srow) * Cdim + dc * 128 + f4c * 4];
            }
            __syncthreads();
#pragma unroll 4
            for (int s = 0; s < 64; ++s) {
                float2 pv = *(const float2*)&Ps[s][ty * 2];
                float4 v0 = *(const float4*)&Vs[s][tx * 8];
                float4 v1 = *(const float4*)&Vs[s][tx * 8 + 4];
                float va[8] = {v0.x, v0.y, v0.z, v0.w, v1.x, v1.y, v1.z, v1.w};
#pragma unroll
                for (int jj = 0; jj < 8; ++jj) {
                    acc[0][dc * 8 + jj] += pv.x * va[jj];
                    acc[1][dc * 8 + jj] += pv.y * va[jj];
                }
            }
        }
    }

    // ---- epilogue: tanh + store
#pragma unroll
    for (int i = 0; i < 2; ++i) {
        size_t ro = (bT + t0 + ty * 2 + i) * (size_t)Cdim;
#pragma unroll
        for (int dc = 0; dc < 4; ++dc) {
            float4 o0, o1;
            o0.x = tanhf(acc[i][dc * 8 + 0]);
            o0.y = tanhf(acc[i][dc * 8 + 1]);
            o0.z = tanhf(acc[i][dc * 8 + 2]);
            o0.w = tanhf(acc[i][dc * 8 + 3]);
            o1.x = tanhf(acc[i][dc * 8 + 4]);
            o1.y = tanhf(acc[i][dc * 8 + 5]);
            o1.z = tanhf(acc[i][dc * 8 + 6]);
            o1.w = tanhf(acc[i][dc * 8 + 7]);
            *(float4*)&O[ro + dc * 128 + tx * 8]     = o0;
            *(float4*)&O[ro + dc * 128 + tx * 8 + 4] = o1;
        }
    }
}

// ---------------------------------------------------------------------------
// Kernel D: S_final[b,c,d] = sum_s exp(L[T]-L[s+1]) K[b,s,c] V[b,s,d]
// 64x64 output tiles, inner dim s in chunks of 16, decay-pruned.
// ---------------------------------------------------------------------------
__global__ __launch_bounds__(256) void sfinal_kernel(
    const float* __restrict__ Km, const float* __restrict__ Vm,
    const float* __restrict__ L, float* __restrict__ S) {
    __shared__ float Ks2[16][68];   // [s][c], K pre-scaled by w_s
    __shared__ float Vs2[16][68];   // [s][d]
    int tid = threadIdx.x;
    int c0 = blockIdx.x * 64, d0 = blockIdx.y * 64;
    int b = blockIdx.z;
    size_t bT = (size_t)b * Tlen;
    float Ltot = L[Tlen];
    int tx = tid & 15, ty = tid >> 4;
    int row = tid >> 4, q = tid & 15;   // 16 rows x 16 f4

    float acc[4][4];
#pragma unroll
    for (int i = 0; i < 4; ++i)
#pragma unroll
        for (int j = 0; j < 4; ++j) acc[i][j] = 0.f;

    for (int s0 = 0; s0 < Tlen; s0 += 16) {
        if (Ltot - L[s0 + 16] < CUT) continue;   // uniform branch: chunk negligible
        float w = expf(Ltot - L[s0 + row + 1]);
        float4 kv = *(const float4*)&Km[(bT + s0 + row) * Cdim + c0 + q * 4];
        float4 vv = *(const float4*)&Vm[(bT + s0 + row) * Cdim + d0 + q * 4];
        __syncthreads();
        Ks2[row][q * 4 + 0] = kv.x * w;
        Ks2[row][q * 4 + 1] = kv.y * w;
        Ks2[row][q * 4 + 2] = kv.z * w;
        Ks2[row][q * 4 + 3] = kv.w * w;
        *(float4*)&Vs2[row][q * 4] = vv;
        __syncthreads();
#pragma unroll
        for (int ss = 0; ss < 16; ++ss) {
            float4 ka = *(const float4*)&Ks2[ss][ty * 4];
            float4 vb = *(const float4*)&Vs2[ss][tx * 4];
            float aa[4] = {ka.x, ka.y, ka.z, ka.w};
            float bb[4] = {vb.x, vb.y, vb.z, vb.w};
#pragma unroll
            for (int i = 0; i < 4; ++i)
#pragma unroll
                for (int j = 0; j < 4; ++j) acc[i][j] += aa[i] * bb[j];
        }
    }
#pragma unroll
    for (int i = 0; i < 4; ++i) {
        float4 o;
        o.x = acc[i][0]; o.y = acc[i][1]; o.z = acc[i][2]; o.w = acc[i][3];
        *(float4*)&S[((size_t)b * Cdim + c0 + ty * 4 + i) * Cdim + d0 + tx * 4] = o;
    }
}

// ---------------------------------------------------------------------------
extern "C" void kernel_launch(void* const* d_in, const int* in_sizes, int n_in,
                              void* d_out, int out_size, void* d_ws, size_t ws_size,
                              hipStream_t stream) {
    (void)in_sizes; (void)n_in; (void)out_size; (void)ws_size;
    const float* X  = (const float*)d_in[0];
    // d_in[1] = S_n: unused (reference zeroes it)
    const float* WQ = (const float*)d_in[2];
    const float* bQ = (const float*)d_in[3];
    const float* WK = (const float*)d_in[4];
    const float* bK = (const float*)d_in[5];
    const float* WV = (const float*)d_in[6];
    const float* bV = (const float*)d_in[7];

    float* out   = (float*)d_out;
    float* S_out = out + (size_t)Bsz * Tlen * Cdim;

    float* ws = (float*)d_ws;
    const size_t qkv = (size_t)Bsz * Tlen * Cdim;   // 8388608
    float* Q = ws;
    float* K = ws + qkv;
    float* V = ws + 2 * qkv;
    float* L = ws + 3 * qkv;        // T+1 entries
    float* A = L + 4112;            // T entries (16B-aligned offset)

    scan_kernel<<<1, 256, 0, stream>>>(L, A);
    qkv_gemm<<<dim3(256, 24), 256, 0, stream>>>(X, WQ, bQ, WK, bK, WV, bV, Q, K, V);
    attn_kernel<<<512, 256, 0, stream>>>(Q, K, V, L, A, out);
    sfinal_kernel<<<dim3(8, 8, Bsz), 256, 0, stream>>>(K, V, L, S_out);
}

// Round 2
// 1234.918 us; speedup vs baseline: 1.6215x; 1.6215x over previous
//
#include <hip/hip_runtime.h>
#include <math.h>

#define Bsz  4
#define Tlen 4096
#define Cdim 512
#define CUT  (-35.0f)

typedef unsigned int u32;
typedef __attribute__((ext_vector_type(8))) __bf16 bf16x8;
typedef __attribute__((ext_vector_type(4))) float floatx4;
#define MFMA16(a,b,c) __builtin_amdgcn_mfma_f32_16x16x32_bf16((a),(b),(c),0,0,0)

__device__ __forceinline__ unsigned short f2bf(float x) {
    u32 u = __float_as_uint(x);
    u32 r = u + 0x7FFFu + ((u >> 16) & 1u);
    return (unsigned short)(r >> 16);
}
__device__ __forceinline__ float bf2f(unsigned short h) {
    return __uint_as_float(((u32)h) << 16);
}

// ---------------------------------------------------------------------------
// Kernel A: prefix sums of ln(gamma).
// ---------------------------------------------------------------------------
__global__ void scan_kernel(float* __restrict__ L, float* __restrict__ A) {
    __shared__ float sums[256];
    int tid = threadIdx.x;
    float lg[16];
    float local = 0.f;
    int base = tid * 16;
#pragma unroll
    for (int i = 0; i < 16; ++i) {
        int t = base + i;
        float g = 0.96f + 0.03f * ((float)t * (1.0f / 4095.0f));
        lg[i] = logf(g);
        local += lg[i];
    }
    sums[tid] = local;
    __syncthreads();
    for (int off = 1; off < 256; off <<= 1) {
        float v = sums[tid];
        if (tid >= off) v += sums[tid - off];
        __syncthreads();
        sums[tid] = v;
        __syncthreads();
    }
    float pre = (tid == 0) ? 0.f : sums[tid - 1];
#pragma unroll
    for (int i = 0; i < 16; ++i) {
        int t = base + i;
        L[t] = pre;
        A[t] = lg[i] + pre;
        pre += lg[i];
    }
    if (tid == 255) L[Tlen] = pre;
}

// ---------------------------------------------------------------------------
// Kernel B: fused QKV projection (fp32 compute) with bf16 hi/lo epilogue.
// Q -> Qhi/Qlo [B*T,C]; K -> Khi/Klo [B*T,C]; V -> VThi/VTlo [B][C][T] (transposed)
// ---------------------------------------------------------------------------
__global__ __launch_bounds__(256) void qkv_gemm(
    const float* __restrict__ X,
    const float* __restrict__ WQ, const float* __restrict__ bQ,
    const float* __restrict__ WK, const float* __restrict__ bK,
    const float* __restrict__ WV, const float* __restrict__ bV,
    unsigned short* __restrict__ Qhi, unsigned short* __restrict__ Qlo,
    unsigned short* __restrict__ Khi, unsigned short* __restrict__ Klo,
    unsigned short* __restrict__ VThi, unsigned short* __restrict__ VTlo) {
    __shared__ float As[16][68];
    __shared__ float Bs[16][68];
    int tid = threadIdx.x;
    int mt = blockIdx.x;
    int nt = blockIdx.y;
    int mat = nt >> 3;
    int n0  = (nt & 7) * 64;
    const float* W    = (mat == 0) ? WQ : (mat == 1) ? WK : WV;
    const float* bias = (mat == 0) ? bQ : (mat == 1) ? bK : bV;
    int m0 = mt * 64;
    int tx = tid & 15, ty = tid >> 4;
    int arow = tid >> 2, aq = tid & 3;
    int brow = tid >> 4, bq = tid & 15;

    float acc[4][4];
#pragma unroll
    for (int i = 0; i < 4; ++i)
#pragma unroll
        for (int j = 0; j < 4; ++j) acc[i][j] = 0.f;

    for (int kc = 0; kc < Cdim; kc += 16) {
        float4 av = *(const float4*)&X[(size_t)(m0 + arow) * Cdim + kc + aq * 4];
        float4 bv = *(const float4*)&W[(size_t)(kc + brow) * Cdim + n0 + bq * 4];
        __syncthreads();
        As[aq * 4 + 0][arow] = av.x;
        As[aq * 4 + 1][arow] = av.y;
        As[aq * 4 + 2][arow] = av.z;
        As[aq * 4 + 3][arow] = av.w;
        *(float4*)&Bs[brow][bq * 4] = bv;
        __syncthreads();
#pragma unroll
        for (int kk = 0; kk < 16; ++kk) {
            float4 a4 = *(const float4*)&As[kk][ty * 4];
            float4 b4 = *(const float4*)&Bs[kk][tx * 4];
            float aa[4] = {a4.x, a4.y, a4.z, a4.w};
            float bb[4] = {b4.x, b4.y, b4.z, b4.w};
#pragma unroll
            for (int i = 0; i < 4; ++i)
#pragma unroll
                for (int j = 0; j < 4; ++j) acc[i][j] += aa[i] * bb[j];
        }
    }
    float4 bb4 = *(const float4*)&bias[n0 + tx * 4];
    float bb[4] = {bb4.x, bb4.y, bb4.z, bb4.w};
    float v[4][4];
    unsigned short h[4][4], l[4][4];
#pragma unroll
    for (int i = 0; i < 4; ++i)
#pragma unroll
        for (int j = 0; j < 4; ++j) {
            v[i][j] = acc[i][j] + bb[j];
            h[i][j] = f2bf(v[i][j]);
            l[i][j] = f2bf(v[i][j] - bf2f(h[i][j]));
        }

    if (mat == 2) {
        // transposed bf16 stores: VT[b][d][t]
        int b = m0 >> 12;
        int tb = (m0 & 4095) + ty * 4;
#pragma unroll
        for (int j = 0; j < 4; ++j) {
            int d = n0 + tx * 4 + j;
            size_t g = ((size_t)(b * Cdim + d)) * Tlen + tb;
            uint2 uh, ul;
            uh.x = (u32)h[0][j] | ((u32)h[1][j] << 16);
            uh.y = (u32)h[2][j] | ((u32)h[3][j] << 16);
            ul.x = (u32)l[0][j] | ((u32)l[1][j] << 16);
            ul.y = (u32)l[2][j] | ((u32)l[3][j] << 16);
            *(uint2*)(VThi + g) = uh;
            *(uint2*)(VTlo + g) = ul;
        }
    } else {
        unsigned short* Hi = (mat == 0) ? Qhi : Khi;
        unsigned short* Lo = (mat == 0) ? Qlo : Klo;
#pragma unroll
        for (int i = 0; i < 4; ++i) {
            size_t g = (size_t)(m0 + ty * 4 + i) * Cdim + n0 + tx * 4;
            uint2 uh, ul;
            uh.x = (u32)h[i][0] | ((u32)h[i][1] << 16);
            uh.y = (u32)h[i][2] | ((u32)h[i][3] << 16);
            ul.x = (u32)l[i][0] | ((u32)l[i][1] << 16);
            ul.y = (u32)l[i][2] | ((u32)l[i][3] << 16);
            *(uint2*)(Hi + g) = uh;
            *(uint2*)(Lo + g) = ul;
        }
    }
}

// ---------------------------------------------------------------------------
// Kernel C: MFMA attention. t-tile 64, s-tile 128, 256 thr (4 waves).
// Split-precision quads: dot4 = (qh+ql)(kh+kl) -> ~fp32-exact in bf16 MFMA.
// s-parity split x2 -> 512 blocks; partials atomicAdd'ed into Oacc (pre-tanh).
// ---------------------------------------------------------------------------
__global__ __launch_bounds__(256, 2) void attn_mfma(
    const unsigned short* __restrict__ Qhi, const unsigned short* __restrict__ Qlo,
    const unsigned short* __restrict__ Khi, const unsigned short* __restrict__ Klo,
    const unsigned short* __restrict__ VThi, const unsigned short* __restrict__ VTlo,
    const float* __restrict__ Lpre, const float* __restrict__ Apre,
    float* __restrict__ Oacc) {
    __shared__ char smem[74752];
    unsigned short* Qs = (unsigned short*)smem;            // [64][72] quad-k chunk
    unsigned short* Ks = (unsigned short*)(smem + 9216);   // [128][72]
    unsigned short* Vs = (unsigned short*)smem;            // [512][40] (aliases Qs/Ks)
    unsigned short* Pq = (unsigned short*)(smem + 40960);  // [64][264]

    int tid = threadIdx.x;
    int lane = tid & 63;
    int wid = tid >> 6;
    int l16 = lane & 15;
    int quad = lane >> 4;

    int bid = blockIdx.x;
    int r = (bid < 256) ? bid : 767 - bid;   // complementary pairing for balance
    int ttile = 63 - (r >> 3);
    int b = (r >> 1) & 3;
    int part = r & 1;
    int t0 = ttile * 64;

    int mw = wid & 1;   // phase-1 t-half of wave
    int nw = wid >> 1;  // phase-1 s-half of wave

    float areg[2][4];
#pragma unroll
    for (int mt = 0; mt < 2; ++mt)
#pragma unroll
        for (int rr = 0; rr < 4; ++rr)
            areg[mt][rr] = Apre[t0 + mw * 32 + mt * 16 + quad * 4 + rr];

    int st_hi = ttile >> 1;
    int s_lo = st_hi;
    float At0 = Apre[t0];
    for (int st = 0; st < st_hi; ++st) {
        if (At0 - Lpre[st * 128 + 128] > CUT) { s_lo = st; break; }
    }

    floatx4 oacc[4][8];
#pragma unroll
    for (int i = 0; i < 4; ++i)
#pragma unroll
        for (int j = 0; j < 8; ++j) oacc[i][j] = (floatx4)0.f;

    for (int st = s_lo; st <= st_hi; ++st) {
        if (((st - s_lo) & 1) != part) continue;
        int s0 = st * 128;
        float lsp[4];
#pragma unroll
        for (int nt = 0; nt < 4; ++nt)
            lsp[nt] = Lpre[s0 + nw * 64 + nt * 16 + l16 + 1];

        floatx4 pacc[2][4];
#pragma unroll
        for (int i = 0; i < 2; ++i)
#pragma unroll
            for (int j = 0; j < 4; ++j) pacc[i][j] = (floatx4)0.f;

        // ---- phase 1: P = Qq . Kq^T  (quad inner dim 2048, chunks of 64)
        for (int kc = 0; kc < 2048; kc += 64) {
            int cb = kc >> 2;   // source fp32-col base, 16 elems per chunk
            __syncthreads();
            for (int t_ = tid; t_ < 384; t_ += 256) {
                if (t_ < 128) {
                    int row = t_ >> 1, half = t_ & 1;
                    size_t g = ((size_t)(b * Tlen + t0 + row)) * Cdim + cb + half * 8;
                    uint4 hu = *(const uint4*)(Qhi + g);
                    uint4 lu = *(const uint4*)(Qlo + g);
                    u32* dst = (u32*)(Qs + row * 72 + half * 32);
                    // Q pattern per elem: (h,l,h,l) -> word duplicated
                    u32 hw[4] = {hu.x, hu.y, hu.z, hu.w};
                    u32 lw[4] = {lu.x, lu.y, lu.z, lu.w};
#pragma unroll
                    for (int p = 0; p < 4; ++p) {
                        u32 wA = (hw[p] & 0xFFFFu) | (lw[p] << 16);
                        u32 wB = (hw[p] >> 16) | (lw[p] & 0xFFFF0000u);
                        uint4 o; o.x = wA; o.y = wA; o.z = wB; o.w = wB;
                        *(uint4*)(dst + p * 4) = o;
                    }
                } else {
                    int t2 = t_ - 128;
                    int row = t2 >> 1, half = t2 & 1;
                    size_t g = ((size_t)(b * Tlen + s0 + row)) * Cdim + cb + half * 8;
                    uint4 hu = *(const uint4*)(Khi + g);
                    uint4 lu = *(const uint4*)(Klo + g);
                    u32* dst = (u32*)(Ks + row * 72 + half * 32);
                    // K pattern per elem: (h,h,l,l)
                    u32 hw[4] = {hu.x, hu.y, hu.z, hu.w};
                    u32 lw[4] = {lu.x, lu.y, lu.z, lu.w};
#pragma unroll
                    for (int p = 0; p < 4; ++p) {
                        uint4 o;
                        o.x = (hw[p] & 0xFFFFu) * 0x10001u;
                        o.y = (lw[p] & 0xFFFFu) * 0x10001u;
                        o.z = (hw[p] >> 16) * 0x10001u;
                        o.w = (lw[p] >> 16) * 0x10001u;
                        *(uint4*)(dst + p * 4) = o;
                    }
                }
            }
            __syncthreads();
#pragma unroll
            for (int ks = 0; ks < 2; ++ks) {
                int ko = ks * 32 + quad * 8;
                bf16x8 af0 = *(const bf16x8*)(Qs + (mw * 32 + l16) * 72 + ko);
                bf16x8 af1 = *(const bf16x8*)(Qs + (mw * 32 + 16 + l16) * 72 + ko);
#pragma unroll
                for (int nt = 0; nt < 4; ++nt) {
                    bf16x8 bf = *(const bf16x8*)(Ks + (nw * 64 + nt * 16 + l16) * 72 + ko);
                    pacc[0][nt] = MFMA16(af0, bf, pacc[0][nt]);
                    pacc[1][nt] = MFMA16(af1, bf, pacc[1][nt]);
                }
            }
        }

        // ---- transition + phase 2, per s-half
#pragma unroll 1
        for (int hh = 0; hh < 2; ++hh) {
            if (nw == hh) {
#pragma unroll
                for (int mt = 0; mt < 2; ++mt)
#pragma unroll
                for (int nt = 0; nt < 4; ++nt)
#pragma unroll
                for (int rr = 0; rr < 4; ++rr) {
                    int tl = mw * 32 + mt * 16 + quad * 4 + rr;
                    int t = t0 + tl;
                    int sl = nt * 16 + l16;
                    int s = s0 + hh * 64 + sl;
                    float p = pacc[mt][nt][rr];
                    float w = (s <= t) ? __expf(areg[mt][rr] - lsp[nt]) : 0.0f;
                    p *= w;
                    unsigned short ph = f2bf(p);
                    unsigned short pl = f2bf(p - bf2f(ph));
                    u32 wrd = (u32)ph | ((u32)pl << 16);
                    u32* dst = (u32*)(Pq + tl * 264 + sl * 4);
                    dst[0] = wrd; dst[1] = wrd;   // quad (Ph,Pl,Ph,Pl)
                }
            }
            __syncthreads();
            for (int kk = 0; kk < 8; ++kk) {
                int ss = s0 + hh * 64 + kk * 8;
#pragma unroll
                for (int rr_ = 0; rr_ < 2; ++rr_) {
                    int d = tid + rr_ * 256;
                    size_t g = ((size_t)(b * Cdim + d)) * Tlen + ss;
                    uint4 hu = *(const uint4*)(VThi + g);
                    uint4 lu = *(const uint4*)(VTlo + g);
                    u32* dst = (u32*)(Vs + d * 40);
                    u32 hw[4] = {hu.x, hu.y, hu.z, hu.w};
                    u32 lw[4] = {lu.x, lu.y, lu.z, lu.w};
#pragma unroll
                    for (int p = 0; p < 4; ++p) {
                        uint4 o;
                        o.x = (hw[p] & 0xFFFFu) * 0x10001u;
                        o.y = (lw[p] & 0xFFFFu) * 0x10001u;
                        o.z = (hw[p] >> 16) * 0x10001u;
                        o.w = (lw[p] >> 16) * 0x10001u;
                        *(uint4*)(dst + p * 4) = o;
                    }
                }
                __syncthreads();
                int ko = quad * 8;
                bf16x8 pa[4];
#pragma unroll
                for (int mt = 0; mt < 4; ++mt)
                    pa[mt] = *(const bf16x8*)(Pq + (mt * 16 + l16) * 264 + kk * 32 + ko);
#pragma unroll
                for (int nt = 0; nt < 8; ++nt) {
                    bf16x8 vb = *(const bf16x8*)(Vs + (wid * 128 + nt * 16 + l16) * 40 + ko);
#pragma unroll
                    for (int mt = 0; mt < 4; ++mt)
                        oacc[mt][nt] = MFMA16(pa[mt], vb, oacc[mt][nt]);
                }
                __syncthreads();
            }
        }
    }

    // ---- epilogue: atomic accumulate partial O (pre-tanh)
#pragma unroll
    for (int mt = 0; mt < 4; ++mt)
#pragma unroll
    for (int nt = 0; nt < 8; ++nt)
#pragma unroll
    for (int rr = 0; rr < 4; ++rr) {
        int t = t0 + mt * 16 + quad * 4 + rr;
        int d = wid * 128 + nt * 16 + l16;
        atomicAdd(Oacc + ((size_t)(b * Tlen + t)) * Cdim + d, oacc[mt][nt][rr]);
    }
}

// ---------------------------------------------------------------------------
// Kernel D: tanh epilogue
// ---------------------------------------------------------------------------
__global__ __launch_bounds__(256) void tanh_kernel(const float* __restrict__ Oa,
                                                   float* __restrict__ out) {
    size_t i = (size_t)blockIdx.x * 256 + threadIdx.x;
    size_t n4 = (size_t)Bsz * Tlen * Cdim / 4;
    for (; i < n4; i += (size_t)gridDim.x * 256) {
        float4 v = ((const float4*)Oa)[i];
        float4 o;
        o.x = tanhf(v.x); o.y = tanhf(v.y); o.z = tanhf(v.z); o.w = tanhf(v.w);
        ((float4*)out)[i] = o;
    }
}

// ---------------------------------------------------------------------------
// Kernel E: S_final from bf16 hi/lo (values bit-identical to fp32 K,V)
// ---------------------------------------------------------------------------
__global__ __launch_bounds__(256) void sfinal_kernel(
    const unsigned short* __restrict__ Khi, const unsigned short* __restrict__ Klo,
    const unsigned short* __restrict__ VThi, const unsigned short* __restrict__ VTlo,
    const float* __restrict__ L, float* __restrict__ S) {
    __shared__ float Ks2[16][68];
    __shared__ float Vs2[16][68];
    int tid = threadIdx.x;
    int c0 = blockIdx.x * 64, d0 = blockIdx.y * 64;
    int b = blockIdx.z;
    float Ltot = L[Tlen];
    int tx = tid & 15, ty = tid >> 4;

    float acc[4][4];
#pragma unroll
    for (int i = 0; i < 4; ++i)
#pragma unroll
        for (int j = 0; j < 4; ++j) acc[i][j] = 0.f;

    for (int s0 = 0; s0 < Tlen; s0 += 16) {
        if (Ltot - L[s0 + 16] < CUT) continue;
        __syncthreads();
        {
            int row = tid >> 4, q = tid & 15;
            float w = __expf(Ltot - L[s0 + row + 1]);
            size_t g = ((size_t)(b * Tlen + s0 + row)) * Cdim + c0 + q * 4;
            uint2 hu = *(const uint2*)(Khi + g);
            uint2 lu = *(const uint2*)(Klo + g);
            float4 kv;
            kv.x = (bf2f((unsigned short)(hu.x & 0xFFFF)) + bf2f((unsigned short)(lu.x & 0xFFFF))) * w;
            kv.y = (bf2f((unsigned short)(hu.x >> 16))    + bf2f((unsigned short)(lu.x >> 16)))    * w;
            kv.z = (bf2f((unsigned short)(hu.y & 0xFFFF)) + bf2f((unsigned short)(lu.y & 0xFFFF))) * w;
            kv.w = (bf2f((unsigned short)(hu.y >> 16))    + bf2f((unsigned short)(lu.y >> 16)))    * w;
            *(float4*)&Ks2[row][q * 4] = kv;
        }
        if (tid < 128) {
            int dd = tid >> 1, half = tid & 1;
            size_t g = ((size_t)(b * Cdim + d0 + dd)) * Tlen + s0 + half * 8;
            uint4 hu = *(const uint4*)(VThi + g);
            uint4 lu = *(const uint4*)(VTlo + g);
            u32 hw[4] = {hu.x, hu.y, hu.z, hu.w};
            u32 lw[4] = {lu.x, lu.y, lu.z, lu.w};
#pragma unroll
            for (int e = 0; e < 8; ++e) {
                unsigned short hb = (unsigned short)((e & 1) ? (hw[e >> 1] >> 16) : (hw[e >> 1] & 0xFFFF));
                unsigned short lb = (unsigned short)((e & 1) ? (lw[e >> 1] >> 16) : (lw[e >> 1] & 0xFFFF));
                Vs2[half * 8 + e][dd] = bf2f(hb) + bf2f(lb);
            }
        }
        __syncthreads();
#pragma unroll
        for (int ss = 0; ss < 16; ++ss) {
            float4 ka = *(const float4*)&Ks2[ss][ty * 4];
            float4 vb = *(const float4*)&Vs2[ss][tx * 4];
            float aa[4] = {ka.x, ka.y, ka.z, ka.w};
            float bb[4] = {vb.x, vb.y, vb.z, vb.w};
#pragma unroll
            for (int i = 0; i < 4; ++i)
#pragma unroll
                for (int j = 0; j < 4; ++j) acc[i][j] += aa[i] * bb[j];
        }
    }
#pragma unroll
    for (int i = 0; i < 4; ++i) {
        float4 o;
        o.x = acc[i][0]; o.y = acc[i][1]; o.z = acc[i][2]; o.w = acc[i][3];
        *(float4*)&S[((size_t)(b * Cdim) + c0 + ty * 4 + i) * Cdim + d0 + tx * 4] = o;
    }
}

// ---------------------------------------------------------------------------
extern "C" void kernel_launch(void* const* d_in, const int* in_sizes, int n_in,
                              void* d_out, int out_size, void* d_ws, size_t ws_size,
                              hipStream_t stream) {
    (void)in_sizes; (void)n_in; (void)out_size; (void)ws_size;
    const float* X  = (const float*)d_in[0];
    const float* WQ = (const float*)d_in[2];
    const float* bQ = (const float*)d_in[3];
    const float* WK = (const float*)d_in[4];
    const float* bK = (const float*)d_in[5];
    const float* WV = (const float*)d_in[6];
    const float* bV = (const float*)d_in[7];

    float* out   = (float*)d_out;
    float* S_out = out + (size_t)Bsz * Tlen * Cdim;

    char* ws = (char*)d_ws;
    const size_t NB = (size_t)Bsz * Tlen * Cdim;          // 8388608 elems
    unsigned short* Qhi  = (unsigned short*)(ws);
    unsigned short* Qlo  = (unsigned short*)(ws + 2 * NB);
    unsigned short* Khi  = (unsigned short*)(ws + 4 * NB);
    unsigned short* Klo  = (unsigned short*)(ws + 6 * NB);
    unsigned short* VThi = (unsigned short*)(ws + 8 * NB);
    unsigned short* VTlo = (unsigned short*)(ws + 10 * NB);
    float* Oacc          = (float*)(ws + 12 * NB);        // 33.5 MB
    float* L             = (float*)(ws + 16 * NB);
    float* A             = L + 4112;

    hipMemsetAsync(Oacc, 0, NB * sizeof(float), stream);
    scan_kernel<<<1, 256, 0, stream>>>(L, A);
    qkv_gemm<<<dim3(256, 24), 256, 0, stream>>>(X, WQ, bQ, WK, bK, WV, bV,
                                                Qhi, Qlo, Khi, Klo, VThi, VTlo);
    attn_mfma<<<512, 256, 0, stream>>>(Qhi, Qlo, Khi, Klo, VThi, VTlo, L, A, Oacc);
    tanh_kernel<<<2048, 256, 0, stream>>>(Oacc, out);
    sfinal_kernel<<<dim3(8, 8, Bsz), 256, 0, stream>>>(Khi, Klo, VThi, VTlo, L, S_out);
}

// Round 3
// 446.594 us; speedup vs baseline: 4.4838x; 2.7652x over previous
//
#include <hip/hip_runtime.h>
#include <math.h>

#define Bsz  4
#define Tlen 4096
#define Cdim 512
#define CUT  (-35.0f)
#define NBE  8388608   // Bsz*Tlen*Cdim

typedef unsigned int u32;
typedef _Float16 f16;
typedef __attribute__((ext_vector_type(8))) _Float16 f16x8;
typedef __attribute__((ext_vector_type(4))) float floatx4;
#define MFMA_F16(a,b,c) __builtin_amdgcn_mfma_f32_16x16x32_f16((a),(b),(c),0,0,0)

__device__ __forceinline__ u32 pack2(f16 a, f16 b) {
    u32 ua = (u32)__builtin_bit_cast(unsigned short, a);
    u32 ub = (u32)__builtin_bit_cast(unsigned short, b);
    return ua | (ub << 16);
}

// ---------------------------------------------------------------------------
// Kernel A: prefix sums of ln(gamma) + decay weights + work partition tables.
// L[t] = sum_{j<t} ln g_j (t=0..T). Note A[t] == L[t+1] bit-exactly.
// Wfin[s] = exp(L[T]-L[s+1]).  sLo[tt] = first live s-tile (128) for t-tile tt
// (64).  Wp[0..64] = prefix sum of live-tile counts (worklist for attn).
// ---------------------------------------------------------------------------
__global__ void scan_kernel(float* __restrict__ Lg, float* __restrict__ Wfin,
                            int* __restrict__ sLo, int* __restrict__ Wp) {
    __shared__ float Lsh[4097];
    __shared__ float sums[256];
    __shared__ int cnts[64];
    int tid = threadIdx.x;
    float lg[16];
    float local = 0.f;
    int base = tid * 16;
#pragma unroll
    for (int i = 0; i < 16; ++i) {
        int t = base + i;
        float g = 0.96f + 0.03f * ((float)t * (1.0f / 4095.0f));
        lg[i] = logf(g);
        local += lg[i];
    }
    sums[tid] = local;
    __syncthreads();
    for (int off = 1; off < 256; off <<= 1) {
        float v = sums[tid];
        if (tid >= off) v += sums[tid - off];
        __syncthreads();
        sums[tid] = v;
        __syncthreads();
    }
    float pre = (tid == 0) ? 0.f : sums[tid - 1];
#pragma unroll
    for (int i = 0; i < 16; ++i) {
        Lsh[base + i] = pre;
        pre += lg[i];
    }
    if (tid == 255) Lsh[4096] = pre;
    __syncthreads();
    for (int t = tid; t < 4097; t += 256) Lg[t] = Lsh[t];
    float LT = Lsh[4096];
    for (int s = tid; s < 4096; s += 256) Wfin[s] = __expf(LT - Lsh[s + 1]);
    if (tid < 64) {
        int t0 = tid * 64;
        float ref = Lsh[t0 + 1];
        int st_hi = tid >> 1;
        int lo = st_hi;
        for (int st = 0; st < st_hi; ++st)
            if (ref - Lsh[st * 128 + 128] > CUT) { lo = st; break; }
        sLo[tid] = lo;
        cnts[tid] = st_hi - lo + 1;
    }
    __syncthreads();
    if (tid == 0) {
        int acc = 0;
        for (int i = 0; i < 64; ++i) { Wp[i] = acc; acc += cnts[i]; }
        Wp[64] = acc;
    }
}

// ---------------------------------------------------------------------------
// Kernel B: X -> f16 hi/lo split (elementwise).
// ---------------------------------------------------------------------------
__global__ __launch_bounds__(256) void prep_x(const float* __restrict__ X,
                                              f16* __restrict__ Xh, f16* __restrict__ Xl) {
    size_t i = ((size_t)blockIdx.x * 256 + threadIdx.x) * 8;
    float4 a = *(const float4*)(X + i);
    float4 b = *(const float4*)(X + i + 4);
    float v[8] = {a.x, a.y, a.z, a.w, b.x, b.y, b.z, b.w};
    f16 h[8], l[8];
#pragma unroll
    for (int j = 0; j < 8; ++j) {
        h[j] = (f16)v[j];
        l[j] = (f16)(v[j] - (float)h[j]);
    }
    uint4 uh, ul;
    uh.x = pack2(h[0], h[1]); uh.y = pack2(h[2], h[3]);
    uh.z = pack2(h[4], h[5]); uh.w = pack2(h[6], h[7]);
    ul.x = pack2(l[0], l[1]); ul.y = pack2(l[2], l[3]);
    ul.z = pack2(l[4], l[5]); ul.w = pack2(l[6], l[7]);
    *(uint4*)(Xh + i) = uh;
    *(uint4*)(Xl + i) = ul;
}

// ---------------------------------------------------------------------------
// Kernel C: W transpose -> WT[mat][n][k] f16 (for MFMA B-fragments).
// ---------------------------------------------------------------------------
__global__ __launch_bounds__(256) void prep_w(const float* __restrict__ WQ,
                                              const float* __restrict__ WK,
                                              const float* __restrict__ WV,
                                              f16* __restrict__ WT) {
    __shared__ f16 tile[64 * 72];
    int mat = blockIdx.z;
    const float* W = (mat == 0) ? WQ : (mat == 1) ? WK : WV;
    int k0 = blockIdx.x * 64, n0 = blockIdx.y * 64;
    int tid = threadIdx.x;
    int row = tid >> 2, q = tid & 3;
    const float* src = W + (size_t)(k0 + row) * Cdim + n0 + q * 16;
    float vv[16];
#pragma unroll
    for (int j = 0; j < 4; ++j) {
        float4 v = *(const float4*)(src + j * 4);
        vv[j * 4 + 0] = v.x; vv[j * 4 + 1] = v.y; vv[j * 4 + 2] = v.z; vv[j * 4 + 3] = v.w;
    }
#pragma unroll
    for (int j = 0; j < 16; ++j) tile[(q * 16 + j) * 72 + row] = (f16)vv[j];
    __syncthreads();
    f16x8 r0 = *(const f16x8*)(tile + row * 72 + q * 16);
    f16x8 r1 = *(const f16x8*)(tile + row * 72 + q * 16 + 8);
    f16* dst = WT + ((size_t)mat * Cdim + n0 + row) * Cdim + k0 + q * 16;
    *(f16x8*)dst = r0;
    *(f16x8*)(dst + 8) = r1;
}

// ---------------------------------------------------------------------------
// Kernel D: QKV projection via f16 MFMA, X split hi/lo (2 products).
// Outputs: Qh,Ql,Kf row-major [b*t][c]; KT,VT transposed [b][c][t].
// ---------------------------------------------------------------------------
__global__ __launch_bounds__(256, 2) void qkv_mfma(
    const f16* __restrict__ Xh, const f16* __restrict__ Xl,
    const f16* __restrict__ WT,
    const float* __restrict__ bQ, const float* __restrict__ bK, const float* __restrict__ bV,
    f16* __restrict__ Qh, f16* __restrict__ Ql,
    f16* __restrict__ Kf, f16* __restrict__ KT, f16* __restrict__ VT) {
    __shared__ char smem[55296];
    f16* sXh = (f16*)smem;              // [128][72]
    f16* sXl = (f16*)(smem + 18432);
    f16* sW  = (f16*)(smem + 36864);
    f16* sB  = (f16*)smem;              // bounce [128][136] = 34816B (aliased)

    int tid = threadIdx.x, lane = tid & 63, wid = tid >> 6;
    int l16 = lane & 15, quad = lane >> 4;
    int wv_m = wid & 1, wv_n = wid >> 1;
    int m0 = blockIdx.x * 128;
    int mat = blockIdx.y >> 2;
    int n0 = (blockIdx.y & 3) * 128;

    floatx4 acc[4][4];
#pragma unroll
    for (int i = 0; i < 4; ++i)
#pragma unroll
        for (int j = 0; j < 4; ++j) acc[i][j] = (floatx4)0.f;

    int row = tid >> 1, half = tid & 1;

    for (int kc = 0; kc < Cdim; kc += 64) {
        __syncthreads();
        {
            const f16* gh = Xh + (size_t)(m0 + row) * Cdim + kc + half * 32;
            const f16* gl = Xl + (size_t)(m0 + row) * Cdim + kc + half * 32;
            const f16* gw = WT + ((size_t)mat * Cdim + n0 + row) * Cdim + kc + half * 32;
            uint4 a0 = *(const uint4*)gh, a1 = *(const uint4*)(gh + 8);
            uint4 a2 = *(const uint4*)(gh + 16), a3 = *(const uint4*)(gh + 24);
            f16* d = sXh + row * 72 + half * 32;
            *(uint4*)d = a0; *(uint4*)(d + 8) = a1; *(uint4*)(d + 16) = a2; *(uint4*)(d + 24) = a3;
            uint4 b0 = *(const uint4*)gl, b1 = *(const uint4*)(gl + 8);
            uint4 b2 = *(const uint4*)(gl + 16), b3 = *(const uint4*)(gl + 24);
            d = sXl + row * 72 + half * 32;
            *(uint4*)d = b0; *(uint4*)(d + 8) = b1; *(uint4*)(d + 16) = b2; *(uint4*)(d + 24) = b3;
            uint4 c0 = *(const uint4*)gw, c1 = *(const uint4*)(gw + 8);
            uint4 c2 = *(const uint4*)(gw + 16), c3 = *(const uint4*)(gw + 24);
            d = sW + row * 72 + half * 32;
            *(uint4*)d = c0; *(uint4*)(d + 8) = c1; *(uint4*)(d + 16) = c2; *(uint4*)(d + 24) = c3;
        }
        __syncthreads();
#pragma unroll
        for (int ks = 0; ks < 2; ++ks) {
            int ko = ks * 32 + quad * 8;
            f16x8 ah[4], al[4], bw[4];
#pragma unroll
            for (int mt = 0; mt < 4; ++mt) {
                ah[mt] = *(const f16x8*)(sXh + (wv_m * 64 + mt * 16 + l16) * 72 + ko);
                al[mt] = *(const f16x8*)(sXl + (wv_m * 64 + mt * 16 + l16) * 72 + ko);
            }
#pragma unroll
            for (int nt = 0; nt < 4; ++nt)
                bw[nt] = *(const f16x8*)(sW + (wv_n * 64 + nt * 16 + l16) * 72 + ko);
#pragma unroll
            for (int mt = 0; mt < 4; ++mt)
#pragma unroll
                for (int nt = 0; nt < 4; ++nt) {
                    acc[mt][nt] = MFMA_F16(ah[mt], bw[nt], acc[mt][nt]);
                    acc[mt][nt] = MFMA_F16(al[mt], bw[nt], acc[mt][nt]);
                }
        }
    }

    const float* bias = (mat == 0) ? bQ : (mat == 1) ? bK : bV;
    float bv[4];
#pragma unroll
    for (int nt = 0; nt < 4; ++nt) bv[nt] = bias[n0 + wv_n * 64 + nt * 16 + l16];
    float cv[4][4][4];
#pragma unroll
    for (int mt = 0; mt < 4; ++mt)
#pragma unroll
        for (int nt = 0; nt < 4; ++nt)
#pragma unroll
            for (int r = 0; r < 4; ++r) cv[mt][nt][r] = acc[mt][nt][r] + bv[nt];

    int b = m0 >> 12;
    int tloc = m0 & 4095;

    if (mat == 2) {
#pragma unroll
        for (int mt = 0; mt < 4; ++mt)
#pragma unroll
            for (int nt = 0; nt < 4; ++nt) {
                int d = n0 + wv_n * 64 + nt * 16 + l16;
                int t = tloc + wv_m * 64 + mt * 16 + quad * 4;
                uint2 w;
                w.x = pack2((f16)cv[mt][nt][0], (f16)cv[mt][nt][1]);
                w.y = pack2((f16)cv[mt][nt][2], (f16)cv[mt][nt][3]);
                *(uint2*)(VT + ((size_t)(b * Cdim + d)) * Tlen + t) = w;
            }
    } else if (mat == 1) {
#pragma unroll
        for (int mt = 0; mt < 4; ++mt)
#pragma unroll
            for (int nt = 0; nt < 4; ++nt) {
                int d = n0 + wv_n * 64 + nt * 16 + l16;
                int t = tloc + wv_m * 64 + mt * 16 + quad * 4;
                uint2 w;
                w.x = pack2((f16)cv[mt][nt][0], (f16)cv[mt][nt][1]);
                w.y = pack2((f16)cv[mt][nt][2], (f16)cv[mt][nt][3]);
                *(uint2*)(KT + ((size_t)(b * Cdim + d)) * Tlen + t) = w;
            }
        __syncthreads();
#pragma unroll
        for (int mt = 0; mt < 4; ++mt)
#pragma unroll
            for (int nt = 0; nt < 4; ++nt)
#pragma unroll
                for (int r = 0; r < 4; ++r)
                    sB[(wv_m * 64 + mt * 16 + quad * 4 + r) * 136 + wv_n * 64 + nt * 16 + l16] =
                        (f16)cv[mt][nt][r];
        __syncthreads();
        {
            int r2 = tid >> 1, h2 = tid & 1;
            f16* dst = Kf + (size_t)(m0 + r2) * Cdim + n0 + h2 * 64;
#pragma unroll
            for (int j = 0; j < 8; ++j)
                *(uint4*)(dst + j * 8) = *(const uint4*)(sB + r2 * 136 + h2 * 64 + j * 8);
        }
    } else {
        __syncthreads();
#pragma unroll
        for (int mt = 0; mt < 4; ++mt)
#pragma unroll
            for (int nt = 0; nt < 4; ++nt)
#pragma unroll
                for (int r = 0; r < 4; ++r)
                    sB[(wv_m * 64 + mt * 16 + quad * 4 + r) * 136 + wv_n * 64 + nt * 16 + l16] =
                        (f16)cv[mt][nt][r];
        __syncthreads();
        {
            int r2 = tid >> 1, h2 = tid & 1;
            f16* dst = Qh + (size_t)(m0 + r2) * Cdim + n0 + h2 * 64;
#pragma unroll
            for (int j = 0; j < 8; ++j)
                *(uint4*)(dst + j * 8) = *(const uint4*)(sB + r2 * 136 + h2 * 64 + j * 8);
        }
        __syncthreads();
#pragma unroll
        for (int mt = 0; mt < 4; ++mt)
#pragma unroll
            for (int nt = 0; nt < 4; ++nt)
#pragma unroll
                for (int r = 0; r < 4; ++r) {
                    float c = cv[mt][nt][r];
                    f16 hh = (f16)c;
                    sB[(wv_m * 64 + mt * 16 + quad * 4 + r) * 136 + wv_n * 64 + nt * 16 + l16] =
                        (f16)(c - (float)hh);
                }
        __syncthreads();
        {
            int r2 = tid >> 1, h2 = tid & 1;
            f16* dst = Ql + (size_t)(m0 + r2) * Cdim + n0 + h2 * 64;
#pragma unroll
            for (int j = 0; j < 8; ++j)
                *(uint4*)(dst + j * 8) = *(const uint4*)(sB + r2 * 136 + h2 * 64 + j * 8);
        }
    }
}

// ---------------------------------------------------------------------------
// Kernel E: attention. t-tile 64 x s-tile 128, worklist-balanced 512 blocks.
// Phase1: P = (Qh+Ql) . K^T (f16, 2 products). Weight+mask, split P->f16 h/l.
// Phase2: Oacc += (Ph+Pl) . V (f16, 2 products), atomic flush per ttile seg.
// ---------------------------------------------------------------------------
__global__ __launch_bounds__(256, 2) void attn_mfma(
    const f16* __restrict__ Qh, const f16* __restrict__ Ql,
    const f16* __restrict__ Kf, const f16* __restrict__ VT,
    const float* __restrict__ Lg,
    const int* __restrict__ sLo, const int* __restrict__ Wp,
    float* __restrict__ Oacc) {
    __shared__ char smem[75776];
    f16* sQh = (f16*)smem;               // [64][72]
    f16* sQl = (f16*)(smem + 9216);
    f16* sK  = (f16*)(smem + 18432);     // [128][72]
    f16* sV  = (f16*)smem;               // [512][40] (aliases phase1 tiles)
    f16* sPh = (f16*)(smem + 40960);     // [64][136]
    f16* sPl = (f16*)(smem + 58368);

    int tid = threadIdx.x, lane = tid & 63, wid = tid >> 6;
    int l16 = lane & 15, quad = lane >> 4;
    int wv_t = wid >> 1, wv_s = wid & 1;

    int b = blockIdx.x >> 7, wb = blockIdx.x & 127;
    int Wtot = Wp[64];
    int i0 = (wb * Wtot) >> 7;
    int i1 = ((wb + 1) * Wtot) >> 7;
    size_t bT = (size_t)b * Tlen;

    int cur = i0;
    int tt = 0;
    while (cur < i1) {
        while (Wp[tt + 1] <= cur) ++tt;
        int t0 = tt * 64;
        int jEnd = min(Wp[tt + 1], i1) - Wp[tt];
        int j = cur - Wp[tt];
        int lo = sLo[tt];
        cur = Wp[tt] + jEnd;

        float aT[2][4];
#pragma unroll
        for (int t2 = 0; t2 < 2; ++t2)
#pragma unroll
            for (int r = 0; r < 4; ++r)
                aT[t2][r] = Lg[t0 + wv_t * 32 + t2 * 16 + quad * 4 + r + 1];

        floatx4 oacc[4][8];
#pragma unroll
        for (int i = 0; i < 4; ++i)
#pragma unroll
            for (int jj = 0; jj < 8; ++jj) oacc[i][jj] = (floatx4)0.f;

        for (; j < jEnd; ++j) {
            int s0 = (lo + j) * 128;
            float lsp[4];
#pragma unroll
            for (int st = 0; st < 4; ++st)
                lsp[st] = Lg[s0 + wv_s * 64 + st * 16 + l16 + 1];

            floatx4 pacc[2][4];
#pragma unroll
            for (int i = 0; i < 2; ++i)
#pragma unroll
                for (int jj = 0; jj < 4; ++jj) pacc[i][jj] = (floatx4)0.f;

            // ---- phase 1
            for (int kc = 0; kc < Cdim; kc += 64) {
                __syncthreads();
                {
                    int r_ = tid >> 2, q_ = tid & 3;
                    const f16* gq = Qh + (bT + t0 + r_) * Cdim + kc + q_ * 16;
                    uint4 u0 = *(const uint4*)gq, u1 = *(const uint4*)(gq + 8);
                    f16* d = sQh + r_ * 72 + q_ * 16;
                    *(uint4*)d = u0; *(uint4*)(d + 8) = u1;
                    const f16* gl = Ql + (bT + t0 + r_) * Cdim + kc + q_ * 16;
                    uint4 v0 = *(const uint4*)gl, v1 = *(const uint4*)(gl + 8);
                    d = sQl + r_ * 72 + q_ * 16;
                    *(uint4*)d = v0; *(uint4*)(d + 8) = v1;
                    int rk = tid >> 1, hk = tid & 1;
                    const f16* gk = Kf + (bT + s0 + rk) * Cdim + kc + hk * 32;
                    uint4 k0 = *(const uint4*)gk, k1 = *(const uint4*)(gk + 8);
                    uint4 k2 = *(const uint4*)(gk + 16), k3 = *(const uint4*)(gk + 24);
                    d = sK + rk * 72 + hk * 32;
                    *(uint4*)d = k0; *(uint4*)(d + 8) = k1;
                    *(uint4*)(d + 16) = k2; *(uint4*)(d + 24) = k3;
                }
                __syncthreads();
#pragma unroll
                for (int ks = 0; ks < 2; ++ks) {
                    int ko = ks * 32 + quad * 8;
                    f16x8 ah0 = *(const f16x8*)(sQh + (wv_t * 32 + l16) * 72 + ko);
                    f16x8 ah1 = *(const f16x8*)(sQh + (wv_t * 32 + 16 + l16) * 72 + ko);
                    f16x8 al0 = *(const f16x8*)(sQl + (wv_t * 32 + l16) * 72 + ko);
                    f16x8 al1 = *(const f16x8*)(sQl + (wv_t * 32 + 16 + l16) * 72 + ko);
#pragma unroll
                    for (int st = 0; st < 4; ++st) {
                        f16x8 bk = *(const f16x8*)(sK + (wv_s * 64 + st * 16 + l16) * 72 + ko);
                        pacc[0][st] = MFMA_F16(ah0, bk, pacc[0][st]);
                        pacc[0][st] = MFMA_F16(al0, bk, pacc[0][st]);
                        pacc[1][st] = MFMA_F16(ah1, bk, pacc[1][st]);
                        pacc[1][st] = MFMA_F16(al1, bk, pacc[1][st]);
                    }
                }
            }

            // ---- weight + mask + split P into LDS
#pragma unroll
            for (int t2 = 0; t2 < 2; ++t2)
#pragma unroll
                for (int st = 0; st < 4; ++st)
#pragma unroll
                    for (int r = 0; r < 4; ++r) {
                        int t = t0 + wv_t * 32 + t2 * 16 + quad * 4 + r;
                        int s = s0 + wv_s * 64 + st * 16 + l16;
                        float p = pacc[t2][st][r];
                        p = (s <= t) ? p * __expf(aT[t2][r] - lsp[st]) : 0.f;
                        f16 ph = (f16)p;
                        f16 pl = (f16)(p - (float)ph);
                        int idx = (wv_t * 32 + t2 * 16 + quad * 4 + r) * 136 +
                                  wv_s * 64 + st * 16 + l16;
                        sPh[idx] = ph;
                        sPl[idx] = pl;
                    }

            // ---- phase 2
#pragma unroll 1
            for (int sc = 0; sc < 4; ++sc) {
                __syncthreads();
#pragma unroll
                for (int p2 = 0; p2 < 2; ++p2) {
                    int d = tid + p2 * 256;
                    const f16* gv = VT + ((size_t)(b * Cdim + d)) * Tlen + s0 + sc * 32;
                    uint4 v0 = *(const uint4*)gv, v1 = *(const uint4*)(gv + 8);
                    uint4 v2 = *(const uint4*)(gv + 16), v3 = *(const uint4*)(gv + 24);
                    f16* dd = sV + d * 40;
                    *(uint4*)dd = v0; *(uint4*)(dd + 8) = v1;
                    *(uint4*)(dd + 16) = v2; *(uint4*)(dd + 24) = v3;
                }
                __syncthreads();
                int ko = quad * 8;
                f16x8 pa[4], pb[4];
#pragma unroll
                for (int mt = 0; mt < 4; ++mt) {
                    pa[mt] = *(const f16x8*)(sPh + (mt * 16 + l16) * 136 + sc * 32 + ko);
                    pb[mt] = *(const f16x8*)(sPl + (mt * 16 + l16) * 136 + sc * 32 + ko);
                }
#pragma unroll
                for (int nt = 0; nt < 8; ++nt) {
                    f16x8 vb = *(const f16x8*)(sV + (wid * 128 + nt * 16 + l16) * 40 + ko);
#pragma unroll
                    for (int mt = 0; mt < 4; ++mt) {
                        oacc[mt][nt] = MFMA_F16(pa[mt], vb, oacc[mt][nt]);
                        oacc[mt][nt] = MFMA_F16(pb[mt], vb, oacc[mt][nt]);
                    }
                }
            }
        }

        // ---- flush partials
#pragma unroll
        for (int mt = 0; mt < 4; ++mt)
#pragma unroll
            for (int nt = 0; nt < 8; ++nt)
#pragma unroll
                for (int r = 0; r < 4; ++r) {
                    int t = t0 + mt * 16 + quad * 4 + r;
                    int d = wid * 128 + nt * 16 + l16;
                    atomicAdd(Oacc + (bT + t) * Cdim + d, oacc[mt][nt][r]);
                }
    }
}

// ---------------------------------------------------------------------------
// Kernel F: tanh epilogue
// ---------------------------------------------------------------------------
__global__ __launch_bounds__(256) void tanh_kernel(const float* __restrict__ Oa,
                                                   float* __restrict__ out) {
    size_t i = (size_t)blockIdx.x * 256 + threadIdx.x;
    size_t n4 = (size_t)NBE / 4;
    for (; i < n4; i += (size_t)gridDim.x * 256) {
        float4 v = ((const float4*)Oa)[i];
        float4 o;
        o.x = tanhf(v.x); o.y = tanhf(v.y); o.z = tanhf(v.z); o.w = tanhf(v.w);
        ((float4*)out)[i] = o;
    }
}

// ---------------------------------------------------------------------------
// Kernel G: S_final = sum_s Wfin[s] * K[s]^T V[s] via f16 MFMA on KT/VT.
// ---------------------------------------------------------------------------
__global__ __launch_bounds__(256) void sfinal_mfma(
    const f16* __restrict__ KT, const f16* __restrict__ VT,
    const float* __restrict__ Lg, const float* __restrict__ Wfin,
    float* __restrict__ S) {
    __shared__ f16 sA[64 * 72];
    __shared__ f16 sB2[64 * 72];
    int tid = threadIdx.x, lane = tid & 63, wid = tid >> 6;
    int l16 = lane & 15, quad = lane >> 4;
    int wv_c = wid & 1, wv_d = wid >> 1;
    int c0 = blockIdx.x * 64, d0 = blockIdx.y * 64, b = blockIdx.z;
    float LT = Lg[Tlen];
    floatx4 acc[2][2];
#pragma unroll
    for (int i = 0; i < 2; ++i)
#pragma unroll
        for (int jj = 0; jj < 2; ++jj) acc[i][jj] = (floatx4)0.f;

    int s0start = Tlen - 64;
    for (int s0 = 0; s0 < Tlen; s0 += 64)
        if (LT - Lg[s0 + 64] > CUT) { s0start = s0; break; }

    int row = tid >> 2, q = tid & 3;
    for (int s0 = s0start; s0 < Tlen; s0 += 64) {
        __syncthreads();
        {
            const f16* g = KT + ((size_t)(b * Cdim + c0 + row)) * Tlen + s0 + q * 16;
            f16x8 u0 = *(const f16x8*)g;
            f16x8 u1 = *(const f16x8*)(g + 8);
            float wv[16];
#pragma unroll
            for (int jj = 0; jj < 4; ++jj) {
                float4 w4 = *(const float4*)(Wfin + s0 + q * 16 + jj * 4);
                wv[jj * 4 + 0] = w4.x; wv[jj * 4 + 1] = w4.y;
                wv[jj * 4 + 2] = w4.z; wv[jj * 4 + 3] = w4.w;
            }
            f16x8 o0, o1;
#pragma unroll
            for (int jj = 0; jj < 8; ++jj) o0[jj] = (f16)((float)u0[jj] * wv[jj]);
#pragma unroll
            for (int jj = 0; jj < 8; ++jj) o1[jj] = (f16)((float)u1[jj] * wv[8 + jj]);
            *(f16x8*)(sA + row * 72 + q * 16) = o0;
            *(f16x8*)(sA + row * 72 + q * 16 + 8) = o1;
            const f16* gv = VT + ((size_t)(b * Cdim + d0 + row)) * Tlen + s0 + q * 16;
            uint4 v0 = *(const uint4*)gv, v1 = *(const uint4*)(gv + 8);
            *(uint4*)(sB2 + row * 72 + q * 16) = v0;
            *(uint4*)(sB2 + row * 72 + q * 16 + 8) = v1;
        }
        __syncthreads();
#pragma unroll
        for (int ks = 0; ks < 2; ++ks) {
            int ko = ks * 32 + quad * 8;
            f16x8 a0 = *(const f16x8*)(sA + (wv_c * 32 + l16) * 72 + ko);
            f16x8 a1 = *(const f16x8*)(sA + (wv_c * 32 + 16 + l16) * 72 + ko);
            f16x8 b0 = *(const f16x8*)(sB2 + (wv_d * 32 + l16) * 72 + ko);
            f16x8 b1 = *(const f16x8*)(sB2 + (wv_d * 32 + 16 + l16) * 72 + ko);
            acc[0][0] = MFMA_F16(a0, b0, acc[0][0]);
            acc[0][1] = MFMA_F16(a0, b1, acc[0][1]);
            acc[1][0] = MFMA_F16(a1, b0, acc[1][0]);
            acc[1][1] = MFMA_F16(a1, b1, acc[1][1]);
        }
    }
#pragma unroll
    for (int ct = 0; ct < 2; ++ct)
#pragma unroll
        for (int dt = 0; dt < 2; ++dt)
#pragma unroll
            for (int r = 0; r < 4; ++r) {
                int c = c0 + wv_c * 32 + ct * 16 + quad * 4 + r;
                int d = d0 + wv_d * 32 + dt * 16 + l16;
                S[((size_t)(b * Cdim + c)) * Cdim + d] = acc[ct][dt][r];
            }
}

// ---------------------------------------------------------------------------
extern "C" void kernel_launch(void* const* d_in, const int* in_sizes, int n_in,
                              void* d_out, int out_size, void* d_ws, size_t ws_size,
                              hipStream_t stream) {
    (void)in_sizes; (void)n_in; (void)out_size; (void)ws_size;
    const float* X  = (const float*)d_in[0];
    const float* WQ = (const float*)d_in[2];
    const float* bQ = (const float*)d_in[3];
    const float* WK = (const float*)d_in[4];
    const float* bK = (const float*)d_in[5];
    const float* WV = (const float*)d_in[6];
    const float* bV = (const float*)d_in[7];

    float* out   = (float*)d_out;
    float* S_out = out + (size_t)NBE;

    char* ws = (char*)d_ws;
    const size_t NB2 = (size_t)NBE * 2;   // bytes of one f16 array
    f16*   Xh   = (f16*)(ws);                       // aliased with Oacc
    f16*   Xl   = (f16*)(ws + NB2);
    float* Oacc = (float*)(ws);                     // 4*NBE bytes, after qkv
    f16*   Qh   = (f16*)(ws + 2 * NB2);
    f16*   Ql   = (f16*)(ws + 3 * NB2);
    f16*   Kf   = (f16*)(ws + 4 * NB2);
    f16*   KT   = (f16*)(ws + 5 * NB2);
    f16*   VT   = (f16*)(ws + 6 * NB2);
    f16*   WT   = (f16*)(ws + 7 * NB2);             // 1.57MB
    char*  tail = ws + 7 * NB2 + 2 * 1024 * 1024;
    float* Lg   = (float*)(tail);                   // 4097 floats
    float* Wfin = (float*)(tail + 16512);           // 4096 floats
    int*   sLo  = (int*)(tail + 16512 + 16384);
    int*   Wp   = (int*)(tail + 16512 + 16384 + 256);

    scan_kernel<<<1, 256, 0, stream>>>(Lg, Wfin, sLo, Wp);
    prep_x<<<4096, 256, 0, stream>>>(X, Xh, Xl);
    prep_w<<<dim3(8, 8, 3), 256, 0, stream>>>(WQ, WK, WV, WT);
    qkv_mfma<<<dim3(128, 12), 256, 0, stream>>>(Xh, Xl, WT, bQ, bK, bV,
                                                Qh, Ql, Kf, KT, VT);
    hipMemsetAsync(Oacc, 0, (size_t)NBE * 4, stream);   // after qkv: aliases Xh/Xl
    attn_mfma<<<512, 256, 0, stream>>>(Qh, Ql, Kf, VT, Lg, sLo, Wp, Oacc);
    tanh_kernel<<<2048, 256, 0, stream>>>(Oacc, out);
    sfinal_mfma<<<dim3(8, 8, Bsz), 256, 0, stream>>>(KT, VT, Lg, Wfin, S_out);
}